// Round 1
// baseline (275.996 us; speedup 1.0000x reference)
//
#include <hip/hip_runtime.h>

typedef int i32x4 __attribute__((ext_vector_type(4)));

#define M_DIM 8192
#define N_DIM 8192
#define K_DIM 2048

// ---------------- quantize x: per-tensor scale, 16 elems/thread ----------------
__global__ __launch_bounds__(256) void quant_x_kernel(
    const float* __restrict__ x, const float* __restrict__ in_scale,
    i32x4* __restrict__ qx, int n16)
{
    int idx = blockIdx.x * 256 + threadIdx.x;
    if (idx >= n16) return;
    float s = in_scale[0];
    const float4* xp = reinterpret_cast<const float4*>(x) + (size_t)idx * 4;
    union { char c[16]; i32x4 v; } u;
#pragma unroll
    for (int v4 = 0; v4 < 4; ++v4) {
        float4 f = xp[v4];
        float q0 = fminf(fmaxf(rintf(f.x / s), -128.f), 127.f);
        float q1 = fminf(fmaxf(rintf(f.y / s), -128.f), 127.f);
        float q2 = fminf(fmaxf(rintf(f.z / s), -128.f), 127.f);
        float q3 = fminf(fmaxf(rintf(f.w / s), -128.f), 127.f);
        u.c[v4*4+0] = (char)(int)q0;
        u.c[v4*4+1] = (char)(int)q1;
        u.c[v4*4+2] = (char)(int)q2;
        u.c[v4*4+3] = (char)(int)q3;
    }
    qx[idx] = u.v;
}

// ---------------- quantize w: per-row (out-channel) scale ----------------
__global__ __launch_bounds__(256) void quant_w_kernel(
    const float* __restrict__ w, const float* __restrict__ w_scale,
    i32x4* __restrict__ qw, int n16)
{
    int idx = blockIdx.x * 256 + threadIdx.x;
    if (idx >= n16) return;
    // 16 elems/thread, K=2048 -> 128 threads per row
    float s = w_scale[idx >> 7];
    const float4* wp = reinterpret_cast<const float4*>(w) + (size_t)idx * 4;
    union { char c[16]; i32x4 v; } u;
#pragma unroll
    for (int v4 = 0; v4 < 4; ++v4) {
        float4 f = wp[v4];
        float q0 = fminf(fmaxf(rintf(f.x / s), -128.f), 127.f);
        float q1 = fminf(fmaxf(rintf(f.y / s), -128.f), 127.f);
        float q2 = fminf(fmaxf(rintf(f.z / s), -128.f), 127.f);
        float q3 = fminf(fmaxf(rintf(f.w / s), -128.f), 127.f);
        u.c[v4*4+0] = (char)(int)q0;
        u.c[v4*4+1] = (char)(int)q1;
        u.c[v4*4+2] = (char)(int)q2;
        u.c[v4*4+3] = (char)(int)q3;
    }
    qw[idx] = u.v;
}

// ---------------- per-out-channel combined scale + dequantized bias ----------------
__global__ __launch_bounds__(256) void prep_kernel(
    const float* __restrict__ bias, const float* __restrict__ in_scale,
    const float* __restrict__ w_scale, const float* __restrict__ b_scale,
    float* __restrict__ oscale, float* __restrict__ obias, int n)
{
    int i = blockIdx.x * 256 + threadIdx.x;
    if (i >= n) return;
    oscale[i] = in_scale[0] * w_scale[i] * 0.5f;   // W_ALPHA
    float bs = b_scale[i];
    float q = fminf(fmaxf(rintf(bias[i] / bs), -128.f), 127.f);
    obias[i] = q * bs * 0.75f;                      // B_BETA
}

// ---------------- int8 GEMM: C[m,o] = sum_k qx[m,k]*qw[o,k]; fp32 epilogue ----------------
// 128x128 tile, BK=64, 4 waves (2x2), each wave 64x64 = 4x4 fragments of 16x16.
// LDS tiles [128][64] int8 (64 B/row) staged via global_load_lds width=16.
__global__ __launch_bounds__(256) void gemm_i8_kernel(
    const char* __restrict__ qx,   // [M][K] int8
    const char* __restrict__ qw,   // [N][K] int8
    const float* __restrict__ oscale,
    const float* __restrict__ obias,
    float* __restrict__ out)       // [M][N] fp32
{
    __shared__ i32x4 lsA[512];   // 128 rows x 64 bytes
    __shared__ i32x4 lsB[512];

    const int t    = threadIdx.x;
    const int lane = t & 63;
    const int wid  = t >> 6;
    const int wr   = wid >> 1;   // wave row 0..1
    const int wc   = wid & 1;    // wave col 0..1

    // XCD-aware swizzle: 4096 blocks, 4096 % 8 == 0 -> simple bijection
    int bid = blockIdx.x;
    int sid = (bid & 7) * 512 + (bid >> 3);
    int trow = sid >> 6, tcol = sid & 63;
    const size_t brow = (size_t)trow * 128;
    const size_t bcol = (size_t)tcol * 128;

    i32x4 acc[4][4];
#pragma unroll
    for (int m = 0; m < 4; ++m)
#pragma unroll
        for (int n = 0; n < 4; ++n)
            acc[m][n] = (i32x4){0, 0, 0, 0};

    // staging: thread t covers LDS row (t>>2)+64*i, byte col (t&3)*16
    const char* gA0 = qx + (brow + (size_t)(t >> 2)) * K_DIM + (t & 3) * 16;
    const char* gB0 = qw + (bcol + (size_t)(t >> 2)) * K_DIM + (t & 3) * 16;

    const int lrow = lane & 15;
    const int kg   = lane >> 4;   // k-group 0..3 (16 bytes each)

    for (int kt = 0; kt < K_DIM; kt += 64) {
#pragma unroll
        for (int i = 0; i < 2; ++i) {
            __builtin_amdgcn_global_load_lds(
                (const __attribute__((address_space(1))) unsigned int*)(gA0 + kt + (size_t)i * 64 * K_DIM),
                (__attribute__((address_space(3))) unsigned int*)&lsA[t + i * 256], 16, 0, 0);
            __builtin_amdgcn_global_load_lds(
                (const __attribute__((address_space(1))) unsigned int*)(gB0 + kt + (size_t)i * 64 * K_DIM),
                (__attribute__((address_space(3))) unsigned int*)&lsB[t + i * 256], 16, 0, 0);
        }
        __syncthreads();   // compiler drains vmcnt before s_barrier

        i32x4 aF[4], bF[4];
#pragma unroll
        for (int m = 0; m < 4; ++m)
            aF[m] = lsA[(wr * 64 + m * 16 + lrow) * 4 + kg];
#pragma unroll
        for (int n = 0; n < 4; ++n)
            bF[n] = lsB[(wc * 64 + n * 16 + lrow) * 4 + kg];

#pragma unroll
        for (int m = 0; m < 4; ++m)
#pragma unroll
            for (int n = 0; n < 4; ++n)
                acc[m][n] = __builtin_amdgcn_mfma_i32_16x16x64_i8(aF[m], bF[n], acc[m][n], 0, 0, 0);

        __syncthreads();
    }

    // epilogue: C/D layout col = lane&15, row = (lane>>4)*4 + j
    const int colq = lane & 15;
    const int rowq = lane >> 4;
#pragma unroll
    for (int n = 0; n < 4; ++n) {
        size_t col = bcol + wc * 64 + n * 16 + colq;
        float sc = oscale[col];
        float bi = obias[col];
#pragma unroll
        for (int m = 0; m < 4; ++m) {
            size_t rbase = brow + wr * 64 + m * 16 + (size_t)rowq * 4;
#pragma unroll
            for (int j = 0; j < 4; ++j) {
                out[(rbase + j) * N_DIM + col] = (float)acc[m][n][j] * sc + bi;
            }
        }
    }
}

extern "C" void kernel_launch(void* const* d_in, const int* in_sizes, int n_in,
                              void* d_out, int out_size, void* d_ws, size_t ws_size,
                              hipStream_t stream) {
    const float* x        = (const float*)d_in[0];
    const float* weight   = (const float*)d_in[1];
    const float* bias     = (const float*)d_in[2];
    const float* in_scale = (const float*)d_in[3];
    const float* w_scale  = (const float*)d_in[4];
    const float* b_scale  = (const float*)d_in[5];
    float* out = (float*)d_out;

    char* ws = (char*)d_ws;
    const size_t xk = (size_t)M_DIM * K_DIM;   // 16,777,216 bytes
    const size_t wk = (size_t)N_DIM * K_DIM;   // 16,777,216 bytes
    char*  qx     = ws;
    char*  qw     = ws + xk;
    float* oscale = (float*)(ws + xk + wk);
    float* obias  = oscale + N_DIM;

    const int n16 = (int)(xk / 16);            // 1,048,576 (= 4096 * 256 exactly)
    quant_x_kernel<<<4096, 256, 0, stream>>>(x, in_scale, (i32x4*)qx, n16);
    quant_w_kernel<<<4096, 256, 0, stream>>>(weight, w_scale, (i32x4*)qw, n16);
    prep_kernel<<<32, 256, 0, stream>>>(bias, in_scale, w_scale, b_scale, oscale, obias, N_DIM);

    gemm_i8_kernel<<<4096, 256, 0, stream>>>(qx, qw, oscale, obias, out);
}

// Round 2
// 241.832 us; speedup vs baseline: 1.1413x; 1.1413x over previous
//
#include <hip/hip_runtime.h>

typedef int i32x4 __attribute__((ext_vector_type(4)));

#define AS1 __attribute__((address_space(1)))
#define AS3 __attribute__((address_space(3)))

#define M_DIM 8192
#define N_DIM 8192
#define K_DIM 2048
#define NT 32   // K-tiles of 64 bytes

// ---------------- quantize x: per-tensor scale, 16 elems/thread ----------------
__global__ __launch_bounds__(256) void quant_x_kernel(
    const float* __restrict__ x, const float* __restrict__ in_scale,
    i32x4* __restrict__ qx, int n16)
{
    int idx = blockIdx.x * 256 + threadIdx.x;
    if (idx >= n16) return;
    float s = in_scale[0];
    const float4* xp = reinterpret_cast<const float4*>(x) + (size_t)idx * 4;
    union { char c[16]; i32x4 v; } u;
#pragma unroll
    for (int v4 = 0; v4 < 4; ++v4) {
        float4 f = xp[v4];
        u.c[v4*4+0] = (char)(int)fminf(fmaxf(rintf(f.x / s), -128.f), 127.f);
        u.c[v4*4+1] = (char)(int)fminf(fmaxf(rintf(f.y / s), -128.f), 127.f);
        u.c[v4*4+2] = (char)(int)fminf(fmaxf(rintf(f.z / s), -128.f), 127.f);
        u.c[v4*4+3] = (char)(int)fminf(fmaxf(rintf(f.w / s), -128.f), 127.f);
    }
    qx[idx] = u.v;
}

// ---------------- quantize w: per-row (out-channel) scale ----------------
__global__ __launch_bounds__(256) void quant_w_kernel(
    const float* __restrict__ w, const float* __restrict__ w_scale,
    i32x4* __restrict__ qw, int n16)
{
    int idx = blockIdx.x * 256 + threadIdx.x;
    if (idx >= n16) return;
    float s = w_scale[idx >> 7];   // K=2048 -> 128 threads (of 16 elems) per row
    const float4* wp = reinterpret_cast<const float4*>(w) + (size_t)idx * 4;
    union { char c[16]; i32x4 v; } u;
#pragma unroll
    for (int v4 = 0; v4 < 4; ++v4) {
        float4 f = wp[v4];
        u.c[v4*4+0] = (char)(int)fminf(fmaxf(rintf(f.x / s), -128.f), 127.f);
        u.c[v4*4+1] = (char)(int)fminf(fmaxf(rintf(f.y / s), -128.f), 127.f);
        u.c[v4*4+2] = (char)(int)fminf(fmaxf(rintf(f.z / s), -128.f), 127.f);
        u.c[v4*4+3] = (char)(int)fminf(fmaxf(rintf(f.w / s), -128.f), 127.f);
    }
    qw[idx] = u.v;
}

// ---------------- per-out-channel combined scale + dequantized bias ----------------
__global__ __launch_bounds__(256) void prep_kernel(
    const float* __restrict__ bias, const float* __restrict__ in_scale,
    const float* __restrict__ w_scale, const float* __restrict__ b_scale,
    float* __restrict__ oscale, float* __restrict__ obias, int n)
{
    int i = blockIdx.x * 256 + threadIdx.x;
    if (i >= n) return;
    oscale[i] = in_scale[0] * w_scale[i] * 0.5f;   // W_ALPHA
    float bs = b_scale[i];
    float q = fminf(fmaxf(rintf(bias[i] / bs), -128.f), 127.f);
    obias[i] = q * bs * 0.75f;                      // B_BETA
}

// ---------------- int8 GEMM: 256x256 tile, 4-deep ring, counted vmcnt ----------------
// 8 waves (2M x 4N), per-wave 128x64 output = 8x4 frags of mfma_i32_16x16x64_i8.
// K-tile = 64 bytes. LDS: 4 bufs x (A 16KB + B 16KB) = 128 KiB.
// Swizzle: 16B-slot' = kg ^ ((row>>1)&3) -> 16 lanes cover all 8 bank-slots x2 (free).
// Staged linear-dest via global_load_lds with inverse-swizzled GLOBAL source (rule 21).
__global__ __launch_bounds__(512, 2) void gemm_i8_kernel(
    const char* __restrict__ qx,   // [M][K] int8
    const char* __restrict__ qw,   // [N][K] int8
    const float* __restrict__ oscale,
    const float* __restrict__ obias,
    float* __restrict__ out)       // [M][N] fp32
{
    __shared__ __align__(16) char ldsA[4 * 16384];
    __shared__ __align__(16) char ldsB[4 * 16384];

    const int t    = threadIdx.x;          // 0..511
    const int lane = t & 63;
    const int wid  = t >> 6;               // 0..7
    const int wm   = wid >> 2;             // 0..1
    const int wn   = wid & 3;              // 0..3

    // XCD-aware swizzle: 1024 blocks, 1024 % 8 == 0 -> bijective
    int bid = blockIdx.x;
    int sid = (bid & 7) * 128 + (bid >> 3);
    const size_t brow = (size_t)(sid >> 5) * 256;
    const size_t bcol = (size_t)(sid & 31) * 256;

    // staging: thread t, call c covers LDS row c*128 + t/4, 16B slot t&3 (linear dest).
    // Global source pre-swizzled: logical slot = (t&3) ^ ((row>>1)&3) = (t&3) ^ ((t>>3)&3).
    const int srow  = t >> 2;
    const int lslot = (t & 3) ^ ((t >> 3) & 3);
    const char* gA = qx + (brow + srow) * K_DIM + lslot * 16;
    const char* gB = qw + (bcol + srow) * K_DIM + lslot * 16;
    char* dstA = ldsA + t * 16;
    char* dstB = ldsB + t * 16;

#define STAGE(tt_) do {                                                              \
    const int bb_ = (tt_) & 3; const int ko_ = (tt_) * 64;                           \
    __builtin_amdgcn_global_load_lds((const AS1 unsigned int*)(gA + ko_),            \
        (AS3 unsigned int*)(dstA + bb_ * 16384), 16, 0, 0);                          \
    __builtin_amdgcn_global_load_lds((const AS1 unsigned int*)(gA + ko_ + 128 * K_DIM), \
        (AS3 unsigned int*)(dstA + bb_ * 16384 + 8192), 16, 0, 0);                   \
    __builtin_amdgcn_global_load_lds((const AS1 unsigned int*)(gB + ko_),            \
        (AS3 unsigned int*)(dstB + bb_ * 16384), 16, 0, 0);                          \
    __builtin_amdgcn_global_load_lds((const AS1 unsigned int*)(gB + ko_ + 128 * K_DIM), \
        (AS3 unsigned int*)(dstB + bb_ * 16384 + 8192), 16, 0, 0);                   \
  } while (0)

    // per-lane fragment read offsets (swizzled), constant across tiles
    const int lrow = lane & 15;
    const int kg   = lane >> 4;            // 16B k-group 0..3
    int offA[8], offB[4];
#pragma unroll
    for (int m = 0; m < 8; ++m) {
        int r = wm * 128 + m * 16 + lrow;
        offA[m] = r * 64 + ((kg ^ ((r >> 1) & 3)) * 16);
    }
#pragma unroll
    for (int n = 0; n < 4; ++n) {
        int r = wn * 64 + n * 16 + lrow;
        offB[n] = r * 64 + ((kg ^ ((r >> 1) & 3)) * 16);
    }

    i32x4 acc[8][4];
#pragma unroll
    for (int m = 0; m < 8; ++m)
#pragma unroll
        for (int n = 0; n < 4; ++n)
            acc[m][n] = (i32x4){0, 0, 0, 0};

    // prologue: tiles 0 and 1 in flight (8 loads/wave)
    STAGE(0);
    STAGE(1);

    for (int tt = 0; tt < NT; ++tt) {
        if (tt + 2 < NT) {
            STAGE(tt + 2);                                  // -> 12 outstanding
            asm volatile("s_waitcnt vmcnt(8)" ::: "memory"); // tile tt's 4 retired
        } else if (tt + 1 < NT) {
            asm volatile("s_waitcnt vmcnt(4)" ::: "memory");
        } else {
            asm volatile("s_waitcnt vmcnt(0)" ::: "memory");
        }
        __builtin_amdgcn_s_barrier();      // all waves' tile-tt loads retired
        asm volatile("" ::: "memory");
        __builtin_amdgcn_sched_barrier(0);

        const char* bA = ldsA + (tt & 3) * 16384;
        const char* bB = ldsB + (tt & 3) * 16384;
        i32x4 aF[8], bF[4];
#pragma unroll
        for (int m = 0; m < 8; ++m) aF[m] = *(const i32x4*)(bA + offA[m]);
#pragma unroll
        for (int n = 0; n < 4; ++n) bF[n] = *(const i32x4*)(bB + offB[n]);

        __builtin_amdgcn_s_setprio(1);
#pragma unroll
        for (int m = 0; m < 8; ++m)
#pragma unroll
            for (int n = 0; n < 4; ++n)
                acc[m][n] = __builtin_amdgcn_mfma_i32_16x16x64_i8(aF[m], bF[n], acc[m][n], 0, 0, 0);
        __builtin_amdgcn_s_setprio(0);
    }
#undef STAGE

    // epilogue: C/D layout col = lane&15, row = (lane>>4)*4 + j
    const int colq = lane & 15;
    const int rowq = lane >> 4;
#pragma unroll
    for (int n = 0; n < 4; ++n) {
        size_t col = bcol + wn * 64 + n * 16 + colq;
        float sc = oscale[col];
        float bi = obias[col];
#pragma unroll
        for (int m = 0; m < 8; ++m) {
            size_t rbase = brow + wm * 128 + m * 16 + (size_t)rowq * 4;
#pragma unroll
            for (int j = 0; j < 4; ++j)
                out[(rbase + j) * N_DIM + col] = (float)acc[m][n][j] * sc + bi;
        }
    }
}

extern "C" void kernel_launch(void* const* d_in, const int* in_sizes, int n_in,
                              void* d_out, int out_size, void* d_ws, size_t ws_size,
                              hipStream_t stream) {
    const float* x        = (const float*)d_in[0];
    const float* weight   = (const float*)d_in[1];
    const float* bias     = (const float*)d_in[2];
    const float* in_scale = (const float*)d_in[3];
    const float* w_scale  = (const float*)d_in[4];
    const float* b_scale  = (const float*)d_in[5];
    float* out = (float*)d_out;

    char* ws = (char*)d_ws;
    const size_t xk = (size_t)M_DIM * K_DIM;
    const size_t wk = (size_t)N_DIM * K_DIM;
    char*  qx     = ws;
    char*  qw     = ws + xk;
    float* oscale = (float*)(ws + xk + wk);
    float* obias  = oscale + N_DIM;

    const int n16 = (int)(xk / 16);   // 1,048,576 = 4096 * 256
    quant_x_kernel<<<4096, 256, 0, stream>>>(x, in_scale, (i32x4*)qx, n16);
    quant_w_kernel<<<4096, 256, 0, stream>>>(weight, w_scale, (i32x4*)qw, n16);
    prep_kernel<<<32, 256, 0, stream>>>(bias, in_scale, w_scale, b_scale, oscale, obias, N_DIM);

    gemm_i8_kernel<<<1024, 512, 0, stream>>>(qx, qw, oscale, obias, out);
}